// Round 8
// baseline (848.109 us; speedup 1.0000x reference)
//
#include <hip/hip_runtime.h>
#include <hip/hip_bf16.h>
#include <math.h>

// Problem constants
#define B_  2
#define T_  1024
#define D_  1024
#define H_  16
#define DK_ 64
#define DV_ 128
#define FH_ 2816
#define M_  (B_ * T_)   // 2048 tokens
#define C_  64          // chunk length
#define NCH (T_ / C_)   // 16 chunks

typedef __attribute__((ext_vector_type(8))) short bf16x8;
typedef __attribute__((ext_vector_type(4))) float f32x4;

// ---------------------------------------------------------------------------
// rmsnorm with fp32 and/or bf16 outputs (either may be null)
__global__ __launch_bounds__(256) void rmsnorm_k(
    const float* __restrict__ x, const float* __restrict__ w,
    float* __restrict__ outf, __hip_bfloat16* __restrict__ outb,
    int D, float eps) {
  const int row = blockIdx.x;
  const float* xr = x + (size_t)row * D;
  float ss = 0.f;
  for (int i = threadIdx.x; i < D; i += blockDim.x) { float v = xr[i]; ss += v * v; }
  for (int off = 32; off > 0; off >>= 1) ss += __shfl_xor(ss, off, 64);
  __shared__ float wsum[4];
  __shared__ float s_scale;
  const int lane = threadIdx.x & 63, wid = threadIdx.x >> 6;
  if (lane == 0) wsum[wid] = ss;
  __syncthreads();
  if (threadIdx.x == 0) {
    float tot = 0.f;
    const int nw = blockDim.x >> 6;
    for (int i = 0; i < nw; ++i) tot += wsum[i];
    s_scale = rsqrtf(tot / (float)D + eps);
  }
  __syncthreads();
  const float sc = s_scale;
  for (int i = threadIdx.x; i < D; i += blockDim.x) {
    const float v = xr[i] * sc * w[i];
    if (outf) outf[(size_t)row * D + i] = v;
    if (outb) outb[(size_t)row * D + i] = __float2bfloat16(v);
  }
}

// ---------------------------------------------------------------------------
// Tiled transpose + fp32->bf16 convert: W[K,N] -> Wt[N,K]
__global__ __launch_bounds__(256) void transpose_bf16_k(
    const float* __restrict__ W, __hip_bfloat16* __restrict__ Wt, int K, int N) {
  __shared__ float t[32][33];
  const int k0 = blockIdx.y * 32, n0 = blockIdx.x * 32;
  const int c = threadIdx.x & 31, r = threadIdx.x >> 5;  // r in 0..7
#pragma unroll
  for (int i = 0; i < 4; ++i)
    t[r + 8 * i][c] = W[(size_t)(k0 + r + 8 * i) * N + n0 + c];
  __syncthreads();
#pragma unroll
  for (int i = 0; i < 4; ++i)
    Wt[(size_t)(n0 + r + 8 * i) * K + k0 + c] = __float2bfloat16(t[c][r + 8 * i]);
}

// ---------------------------------------------------------------------------
__device__ __forceinline__ void gload_lds16(const void* g, void* l) {
  __builtin_amdgcn_global_load_lds(
      (const __attribute__((address_space(1))) void*)g,
      (__attribute__((address_space(3))) void*)l, 16, 0, 0);
}

// bf16 MFMA GEMM: C[M,N] = A[M,K] @ Bt[N,K]^T.  Tile 128 x BN (BN=128 or 64).
// mode 0: C = acc (fp32); mode 1: C = acc + res (fp32);
// mode 2: Cbf16 = silu(res) * acc   (fused SwiGLU epilogue)
template<int BN>
__global__ __launch_bounds__(256) void mfma_gemm_k(
    const __hip_bfloat16* __restrict__ A, const __hip_bfloat16* __restrict__ Bt,
    const float* __restrict__ res, void* __restrict__ Cout,
    int M, int N, int K, int mode) {
  __shared__ __hip_bfloat16 As[128 * 32];
  __shared__ __hip_bfloat16 Bs[BN * 32];
  constexpr int NF = BN / 32;
  const int tid = threadIdx.x;
  const int lane = tid & 63;
  const int wv = tid >> 6;
  const int wm = (wv >> 1) * 64, wn = (wv & 1) * (BN / 2);
  const int bm = blockIdx.y * 128, bn = blockIdx.x * BN;
  const int l15 = lane & 15, lq8 = (lane >> 4) * 8;
  const int ar = tid >> 2;
  const int ac = (tid & 3) * 8;
  const size_t Abase = (size_t)(bm + ar) * K + ac;
  const size_t Bbase = (size_t)(bn + ar) * K + ac;
  f32x4 acc[4][NF];
#pragma unroll
  for (int i = 0; i < 4; ++i)
#pragma unroll
    for (int j = 0; j < NF; ++j) acc[i][j] = (f32x4){0.f, 0.f, 0.f, 0.f};
  for (int k0 = 0; k0 < K; k0 += 32) {
    gload_lds16(A + Abase + k0, (char*)As + tid * 16);
    gload_lds16(A + Abase + (size_t)64 * K + k0, (char*)As + tid * 16 + 4096);
    gload_lds16(Bt + Bbase + k0, (char*)Bs + tid * 16);
    if (BN == 128)
      gload_lds16(Bt + Bbase + (size_t)64 * K + k0, (char*)Bs + tid * 16 + 4096);
    __syncthreads();
    bf16x8 af[4], bfr[NF];
#pragma unroll
    for (int i = 0; i < 4; ++i)
      af[i] = *(const bf16x8*)(As + (wm + i * 16 + l15) * 32 + lq8);
#pragma unroll
    for (int j = 0; j < NF; ++j)
      bfr[j] = *(const bf16x8*)(Bs + (wn + j * 16 + l15) * 32 + lq8);
#pragma unroll
    for (int i = 0; i < 4; ++i)
#pragma unroll
      for (int j = 0; j < NF; ++j)
        acc[i][j] = __builtin_amdgcn_mfma_f32_16x16x32_bf16(af[i], bfr[j], acc[i][j], 0, 0, 0);
    __syncthreads();
  }
  const int r0 = (lane >> 4) * 4;
#pragma unroll
  for (int i = 0; i < 4; ++i) {
#pragma unroll
    for (int j = 0; j < NF; ++j) {
      const int row = bm + wm + i * 16 + r0;
      const int col = bn + wn + j * 16 + l15;
#pragma unroll
      for (int r = 0; r < 4; ++r) {
        const size_t idx = (size_t)(row + r) * N + col;
        const float a = acc[i][j][r];
        if (mode == 0) ((float*)Cout)[idx] = a;
        else if (mode == 1) ((float*)Cout)[idx] = a + res[idx];
        else {
          const float s = res[idx];
          ((__hip_bfloat16*)Cout)[idx] =
              __float2bfloat16(s * (1.f / (1.f + __expf(-s))) * a);
        }
      }
    }
  }
}

// ---------------------------------------------------------------------------
// pa/pb = h @ [Wa|Wb] — all 256 threads active (8-way K-split + reduce).
__global__ __launch_bounds__(256) void skinny_k(
    const float* __restrict__ h, const float* __restrict__ Wa,
    const float* __restrict__ Wb, float* __restrict__ pa,
    float* __restrict__ pb, int K) {
  __shared__ float hl[D_];
  __shared__ float red[8][32];
  const int row = blockIdx.x;
  const int tid = threadIdx.x;
  {
    const float4* src = (const float4*)(h + (size_t)row * K);
    ((float4*)hl)[tid] = src[tid];
  }
  __syncthreads();
  const int col = tid & 31, sub = tid >> 5;
  const float* W = (col < 16) ? Wa : Wb;
  const int cc = col & 15;
  float s = 0.f;
  const int kk0 = sub * 128;
  for (int k = kk0; k < kk0 + 128; ++k) s += hl[k] * W[k * H_ + cc];
  red[sub][col] = s;
  __syncthreads();
  if (tid < 32) {
    float t = 0.f;
#pragma unroll
    for (int i = 0; i < 8; ++i) t += red[i][tid];
    if (tid < 16) pa[(size_t)row * H_ + tid] = t;
    else          pb[(size_t)row * H_ + tid - 16] = t;
  }
}

// ---------------------------------------------------------------------------
// Plain causal conv + silu (used for v, C=2048)
__global__ __launch_bounds__(256) void conv_silu_k(
    const float* __restrict__ src, const float* __restrict__ w,
    float* __restrict__ dst, int C) {
  const int bt = blockIdx.x;
  const int b = bt / T_, t = bt % T_;
  const float* s = src + (size_t)b * T_ * C;
  for (int c = threadIdx.x; c < C; c += blockDim.x) {
    const float w0 = w[c * 4 + 0], w1 = w[c * 4 + 1],
                w2 = w[c * 4 + 2], w3 = w[c * 4 + 3];
    float acc = s[(size_t)t * C + c] * w3;
    if (t >= 1) acc += s[(size_t)(t - 1) * C + c] * w2;
    if (t >= 2) acc += s[(size_t)(t - 2) * C + c] * w1;
    if (t >= 3) acc += s[(size_t)(t - 3) * C + c] * w0;
    dst[(size_t)bt * C + c] = acc * (1.f / (1.f + __expf(-acc)));
  }
}

// ---------------------------------------------------------------------------
// Fused causal conv + silu + per-head l2norm (+scale) for q/k (C=1024, DK=64).
__global__ __launch_bounds__(256) void conv_silu_l2_k(
    const float* __restrict__ src, const float* __restrict__ w,
    float* __restrict__ dst, float scale) {
  const int bt = blockIdx.x;
  const int b = bt >> 10, t = bt & 1023;
  const float* s = src + (size_t)b * T_ * 1024;
  __shared__ float vals[1024];
  __shared__ float hsc[16];
  const int tid = threadIdx.x;
#pragma unroll
  for (int q = 0; q < 4; ++q) {
    const int c = tid + q * 256;
    const float w0 = w[c * 4 + 0], w1 = w[c * 4 + 1],
                w2 = w[c * 4 + 2], w3 = w[c * 4 + 3];
    float acc = s[(size_t)t * 1024 + c] * w3;
    if (t >= 1) acc += s[(size_t)(t - 1) * 1024 + c] * w2;
    if (t >= 2) acc += s[(size_t)(t - 2) * 1024 + c] * w1;
    if (t >= 3) acc += s[(size_t)(t - 3) * 1024 + c] * w0;
    vals[c] = acc * (1.f / (1.f + __expf(-acc)));
  }
  __syncthreads();
  {
    const int hh = tid >> 4, j = tid & 15;   // 16 threads per head
    float ssum = 0.f;
#pragma unroll
    for (int e = 0; e < 4; ++e) {
      const float v = vals[hh * 64 + j * 4 + e];
      ssum += v * v;
    }
    ssum += __shfl_xor(ssum, 1, 64);
    ssum += __shfl_xor(ssum, 2, 64);
    ssum += __shfl_xor(ssum, 4, 64);
    ssum += __shfl_xor(ssum, 8, 64);
    if (j == 0) hsc[hh] = rsqrtf(ssum + 1e-6f) * scale;
  }
  __syncthreads();
#pragma unroll
  for (int q = 0; q < 4; ++q) {
    const int c = tid + q * 256;
    dst[(size_t)bt * 1024 + c] = vals[c] * hsc[c >> 6];
  }
}

// ---------------------------------------------------------------------------
__global__ void beta_g_k(const float* __restrict__ pa, const float* __restrict__ pb,
                         const float* __restrict__ dtb, const float* __restrict__ Alog,
                         float* __restrict__ g, float* __restrict__ beta, int n) {
  const int i = blockIdx.x * blockDim.x + threadIdx.x;
  if (i >= n) return;
  const int h = i & (H_ - 1);
  const float xx = pa[i] + dtb[h];
  const float sp = (xx > 20.f) ? xx : log1pf(expf(xx));
  g[i] = -expf(Alog[h]) * sp;
  beta[i] = 1.f / (1.f + expf(-pb[i]));
}

// ---------------------------------------------------------------------------
// Chunked gated delta rule, phase A (unchanged from round 7: blocked forward
// substitution, no spills).
__global__ __launch_bounds__(256) void chunk_prep_k(
    const float* __restrict__ q, float* __restrict__ k, float* __restrict__ v,
    const float* __restrict__ g, const float* __restrict__ beta,
    float* __restrict__ qkd, float* __restrict__ kdt, float* __restrict__ gam) {
  const int task = blockIdx.x;
  const int bh = task >> 4, n = task & (NCH - 1);
  const int b = bh >> 4, h = bh & 15;
  const int t0 = n * C_;
  const int tid = threadIdx.x;
  __shared__ float lk[C_][68];
  __shared__ float Gs[C_][68];
  __shared__ float Xs[C_][100];
  __shared__ float Td[4][16][17];
  __shared__ float lb[C_], lgam[C_], lbeta[C_], lbg[C_];
  {
    const int r = tid >> 2, cq = (tid & 3) * 16;
    const float* src = k + (((size_t)b * T_ + t0 + r) * H_ + h) * DK_ + cq;
#pragma unroll
    for (int i = 0; i < 4; ++i)
      *(float4*)&lk[r][cq + 4 * i] = ((const float4*)src)[i];
  }
  if (tid < 64) {
    const size_t gi = ((size_t)b * T_ + t0 + tid) * H_ + h;
    float xx = g[gi];
    const float bb = beta[gi];
    lbeta[tid] = bb;
#pragma unroll
    for (int off = 1; off < 64; off <<= 1) {
      float y = __shfl_up(xx, off, 64);
      if (tid >= off) xx += y;
    }
    lb[tid] = xx;
    const float gm = __expf(xx);
    lgam[tid] = gm;
    lbg[tid] = bb * gm;
  }
  __syncthreads();
  const int r4g = (tid >> 4) * 4;
  const int sl = tid & 15;
  {
    const float* qg = q + (((size_t)b * T_ + t0) * H_ + h) * DK_;
    float accA[4][4] = {};
    float accQ[4][4] = {};
    for (int d = 0; d < 64; d += 4) {
      float4 kt[4], ks[4], qt[4];
#pragma unroll
      for (int i = 0; i < 4; ++i) kt[i] = *(const float4*)&lk[r4g + i][d];
#pragma unroll
      for (int j = 0; j < 4; ++j) ks[j] = *(const float4*)&lk[sl + 16 * j][d];
#pragma unroll
      for (int i = 0; i < 4; ++i) qt[i] = *(const float4*)(qg + (size_t)(r4g + i) * (H_ * DK_) + d);
#pragma unroll
      for (int i = 0; i < 4; ++i)
#pragma unroll
        for (int j = 0; j < 4; ++j) {
          accA[i][j] += kt[i].x * ks[j].x + kt[i].y * ks[j].y + kt[i].z * ks[j].z + kt[i].w * ks[j].w;
          accQ[i][j] += qt[i].x * ks[j].x + qt[i].y * ks[j].y + qt[i].z * ks[j].z + qt[i].w * ks[j].w;
        }
    }
    float* qo = qkd + (size_t)task * 4096;
#pragma unroll
    for (int i = 0; i < 4; ++i)
#pragma unroll
      for (int j = 0; j < 4; ++j) {
        const int t = r4g + i, s = sl + 16 * j;
        const float dec = (s <= t) ? __expf(lb[t] - lb[s]) : 0.f;
        Gs[t][s] = (t > s) ? lbeta[t] * accA[i][j] * dec : 0.f;
        qo[t * 64 + s] = accQ[i][j] * dec;
      }
  }
  {
    const int dk = tid >> 2, s0 = (tid & 3) * 16;
    const float bC = lb[63];
    float* dst = kdt + (size_t)task * 4096 + dk * 64 + s0;
#pragma unroll
    for (int j = 0; j < 16; ++j)
      dst[j] = lk[s0 + j][dk] * __expf(bC - lb[s0 + j]);
  }
  if (tid < 64) gam[(size_t)task * 64 + tid] = lgam[tid];
  __syncthreads();
  if (tid < 64) {
    const int blk = tid >> 4, cI = tid & 15;
    float Xc[16];
#pragma unroll
    for (int t = 0; t < 16; ++t) Xc[t] = (t == cI) ? 1.f : 0.f;
#pragma unroll
    for (int t = 1; t < 16; ++t) {
      float acc = 0.f;
#pragma unroll
      for (int s = 0; s < t; ++s)
        acc += Gs[blk * 16 + t][blk * 16 + s] * Xc[s];
      Xc[t] -= acc;
    }
#pragma unroll
    for (int t = 0; t < 16; ++t) Td[blk][t][cI] = Xc[t];
  } else {
    for (int idx = tid - 64; idx < 64 * 96; idx += 192) {
      const int t = idx / 96, c = idx % 96;
      Xs[t][c] = lbeta[t] * v[(((size_t)b * T_ + t0 + t) * H_ + h) * DV_ + c];
    }
  }
  __syncthreads();
  const int rt = tid & 15;
  const int cg = tid >> 4;
#pragma unroll 1
  for (int half = 0; half < 2; ++half) {
#pragma unroll
    for (int bi = 0; bi < 4; ++bi) {
      if (bi > 0) {
        float acc[6] = {0.f, 0.f, 0.f, 0.f, 0.f, 0.f};
        for (int kk = 0; kk < 16 * bi; ++kk) {
          const float gvv = Gs[16 * bi + rt][kk];
#pragma unroll
          for (int c = 0; c < 6; ++c) acc[c] += gvv * Xs[kk][cg * 6 + c];
        }
#pragma unroll
        for (int c = 0; c < 6; ++c) Xs[16 * bi + rt][cg * 6 + c] -= acc[c];
      }
      __syncthreads();
      float y[6] = {0.f, 0.f, 0.f, 0.f, 0.f, 0.f};
#pragma unroll
      for (int s = 0; s < 16; ++s) {
        const float tv = Td[bi][rt][s];
#pragma unroll
        for (int c = 0; c < 6; ++c) y[c] += tv * Xs[16 * bi + s][cg * 6 + c];
      }
      __syncthreads();
#pragma unroll
      for (int c = 0; c < 6; ++c) Xs[16 * bi + rt][cg * 6 + c] = y[c];
      __syncthreads();
    }
    if (half == 0) {
      for (int idx = tid; idx < 64 * 96; idx += 256) {
        const int t = idx / 96, c = idx % 96;
        v[(((size_t)b * T_ + t0 + t) * H_ + h) * DV_ + c] = Xs[t][c];
      }
      __syncthreads();
      for (int idx = tid; idx < 64 * 96; idx += 256) {
        const int t = idx / 96, c = idx % 96;
        if (c < 32)
          Xs[t][c] = lbeta[t] * v[(((size_t)b * T_ + t0 + t) * H_ + h) * DV_ + 96 + c];
        else
          Xs[t][c] = lbg[t] * lk[t][c - 32];
      }
      __syncthreads();
    } else {
      for (int idx = tid; idx < 64 * 96; idx += 256) {
        const int t = idx / 96, c = idx % 96;
        if (c < 32)
          v[(((size_t)b * T_ + t0 + t) * H_ + h) * DV_ + 96 + c] = Xs[t][c];
        else
          k[(((size_t)b * T_ + t0 + t) * H_ + h) * DK_ + c - 32] = Xs[t][c];
      }
    }
  }
}

// ---------------------------------------------------------------------------
// Serial recurrence v2: async double-buffered global_load_lds staging with
// XOR-granule swizzle (slot = granule ^ (row>>2) -> 2-way banks, free),
// prefetched one chunk ahead; u/gamma prefetched in registers. Single wave,
// no barriers; one s_waitcnt(0) per chunk.
__global__ __launch_bounds__(64) void chunk_rec_k(
    const float* __restrict__ W, float* __restrict__ u,
    const float* __restrict__ kdt, const float* __restrict__ gam,
    float* __restrict__ Sst) {
  const int bh = blockIdx.x >> 3, cg = blockIdx.x & 7;
  const int b = bh >> 4, h = bh & 15;
  const int c0 = cg * 16;
  const int lane = threadIdx.x;
  const int m = lane & 15;          // row-group: rows 4m..4m+3
  const int cl = (lane >> 4) * 4;   // local col tile (0,4,8,12)
  const int lrow = lane >> 4, lcol = lane & 15;   // staging decomposition
  __shared__ float Wn[2][64 * 64];  // swizzled row-major (t-major)
  __shared__ float Kn[2][64 * 64];  // swizzled row-major (dk-major)
  __shared__ float Ss[64][20];      // S[dk][c]
  __shared__ float Ub[64][20];      // Û[t][c]
  float Sr[4][4];
#pragma unroll
  for (int i = 0; i < 4; ++i)
#pragma unroll
    for (int j = 0; j < 4; ++j) Sr[i][j] = 0.f;
  for (int i = lane; i < 64 * 20; i += 64) (&Ss[0][0])[i] = 0.f;
  const size_t Wrow0 = (((size_t)b * T_) * H_ + h) * (size_t)DK_;
  const size_t urow0 = (((size_t)b * T_) * H_ + h) * (size_t)DV_;
  // issue stage for chunk 0
#pragma unroll
  for (int p = 0; p < 16; ++p) {
    gload_lds16(W + Wrow0 + (size_t)(4 * p + lrow) * (H_ * DK_) + ((lcol ^ p) << 2),
                (char*)Wn[0] + p * 1024 + lane * 16);
    gload_lds16(kdt + (size_t)(bh * NCH) * 4096 + (4 * p + lrow) * 64 + ((lcol ^ p) << 2),
                (char*)Kn[0] + p * 1024 + lane * 16);
  }
  // prefetch u / gamma for chunk 0
  float4 uP[4];
#pragma unroll
  for (int i = 0; i < 4; ++i)
    uP[i] = *(const float4*)(u + urow0 + (size_t)(4 * m + i) * (H_ * DV_) + c0 + cl);
  float gCP = gam[(size_t)(bh * NCH) * 64 + 63];
  for (int n = 0; n < NCH; ++n) {
    const int task = bh * NCH + n;
    const int t0 = n * C_;
    const int buf = n & 1;
    const float* Wb_ = Wn[buf];
    const float* Kb_ = Kn[buf];
    __builtin_amdgcn_s_waitcnt(0);   // staged LDS + uP ready
    // issue stage for chunk n+1 into the other buffer
    if (n + 1 < NCH) {
      const size_t Wnext = Wrow0 + (size_t)(t0 + C_) * (H_ * DK_);
      const float* Knext = kdt + (size_t)(task + 1) * 4096;
#pragma unroll
      for (int p = 0; p < 16; ++p) {
        gload_lds16(W + Wnext + (size_t)(4 * p + lrow) * (H_ * DK_) + ((lcol ^ p) << 2),
                    (char*)Wn[buf ^ 1] + p * 1024 + lane * 16);
        gload_lds16(Knext + (4 * p + lrow) * 64 + ((lcol ^ p) << 2),
                    (char*)Kn[buf ^ 1] + p * 1024 + lane * 16);
      }
    }
    // dump chunk-start S
#pragma unroll
    for (int i = 0; i < 4; ++i)
      *(float4*)(Sst + (size_t)task * 8192 + (4 * m + i) * 128 + c0 + cl) =
          make_float4(Sr[i][0], Sr[i][1], Sr[i][2], Sr[i][3]);
    // phase A: acc = u - W·S   (rows t = 4m+i)
    float acc[4][4];
#pragma unroll
    for (int i = 0; i < 4; ++i) {
      acc[i][0] = uP[i].x; acc[i][1] = uP[i].y;
      acc[i][2] = uP[i].z; acc[i][3] = uP[i].w;
    }
    const float gC = gCP;
    // prefetch u / gamma for chunk n+1 (disjoint rows from this chunk's stores)
    if (n + 1 < NCH) {
#pragma unroll
      for (int i = 0; i < 4; ++i)
        uP[i] = *(const float4*)(u + urow0 + (size_t)(t0 + C_ + 4 * m + i) * (H_ * DV_) + c0 + cl);
      gCP = gam[(size_t)(task + 1) * 64 + 63];
    }
    for (int g = 0; g < 16; ++g) {
      const int sw = (g ^ m) << 2;
      float4 a0 = *(const float4*)&Wb_[(4 * m + 0) * 64 + sw];
      float4 a1 = *(const float4*)&Wb_[(4 * m + 1) * 64 + sw];
      float4 a2 = *(const float4*)&Wb_[(4 * m + 2) * 64 + sw];
      float4 a3 = *(const float4*)&Wb_[(4 * m + 3) * 64 + sw];
      float4 s0 = *(const float4*)&Ss[4 * g + 0][cl];
      float4 s1 = *(const float4*)&Ss[4 * g + 1][cl];
      float4 s2 = *(const float4*)&Ss[4 * g + 2][cl];
      float4 s3 = *(const float4*)&Ss[4 * g + 3][cl];
      const float4 aa[4] = {a0, a1, a2, a3};
#pragma unroll
      for (int i = 0; i < 4; ++i) {
        acc[i][0] -= aa[i].x * s0.x + aa[i].y * s1.x + aa[i].z * s2.x + aa[i].w * s3.x;
        acc[i][1] -= aa[i].x * s0.y + aa[i].y * s1.y + aa[i].z * s2.y + aa[i].w * s3.y;
        acc[i][2] -= aa[i].x * s0.z + aa[i].y * s1.z + aa[i].z * s2.z + aa[i].w * s3.z;
        acc[i][3] -= aa[i].x * s0.w + aa[i].y * s1.w + aa[i].z * s2.w + aa[i].w * s3.w;
      }
    }
    // write Û to LDS + global (in place over u, this chunk's rows)
#pragma unroll
    for (int i = 0; i < 4; ++i) {
      *(float4*)&Ub[4 * m + i][cl] = make_float4(acc[i][0], acc[i][1], acc[i][2], acc[i][3]);
      *(float4*)(u + urow0 + (size_t)(t0 + 4 * m + i) * (H_ * DV_) + c0 + cl) =
          make_float4(acc[i][0], acc[i][1], acc[i][2], acc[i][3]);
    }
    // phase B: S = gC·S + KdT·Û   (rows dk = 4m+i)
    float acc2[4][4] = {};
    for (int g = 0; g < 16; ++g) {
      const int sw = (g ^ m) << 2;
      float4 a0 = *(const float4*)&Kb_[(4 * m + 0) * 64 + sw];
      float4 a1 = *(const float4*)&Kb_[(4 * m + 1) * 64 + sw];
      float4 a2 = *(const float4*)&Kb_[(4 * m + 2) * 64 + sw];
      float4 a3 = *(const float4*)&Kb_[(4 * m + 3) * 64 + sw];
      float4 u0 = *(const float4*)&Ub[4 * g + 0][cl];
      float4 u1 = *(const float4*)&Ub[4 * g + 1][cl];
      float4 u2 = *(const float4*)&Ub[4 * g + 2][cl];
      float4 u3 = *(const float4*)&Ub[4 * g + 3][cl];
      const float4 aa[4] = {a0, a1, a2, a3};
#pragma unroll
      for (int i = 0; i < 4; ++i) {
        acc2[i][0] += aa[i].x * u0.x + aa[i].y * u1.x + aa[i].z * u2.x + aa[i].w * u3.x;
        acc2[i][1] += aa[i].x * u0.y + aa[i].y * u1.y + aa[i].z * u2.y + aa[i].w * u3.y;
        acc2[i][2] += aa[i].x * u0.z + aa[i].y * u1.z + aa[i].z * u2.z + aa[i].w * u3.z;
        acc2[i][3] += aa[i].x * u0.w + aa[i].y * u1.w + aa[i].z * u2.w + aa[i].w * u3.w;
      }
    }
#pragma unroll
    for (int i = 0; i < 4; ++i)
#pragma unroll
      for (int c = 0; c < 4; ++c) Sr[i][c] = gC * Sr[i][c] + acc2[i][c];
#pragma unroll
    for (int i = 0; i < 4; ++i)
      *(float4*)&Ss[4 * m + i][cl] = make_float4(Sr[i][0], Sr[i][1], Sr[i][2], Sr[i][3]);
  }
}

// ---------------------------------------------------------------------------
// Parallel O with fused gatenorm (unchanged from round 6/7).
__global__ __launch_bounds__(128) void chunk_o_k(
    const float* __restrict__ q, const float* __restrict__ qkd,
    const float* __restrict__ ub, const float* __restrict__ Sst,
    const float* __restrict__ gam, const float* __restrict__ gate,
    const float* __restrict__ onw, __hip_bfloat16* __restrict__ go) {
  const int task = blockIdx.x;
  const int bh = task >> 4, n = task & 15;
  const int b = bh >> 4, h = bh & 15;
  const int t0 = n * C_;
  const int tid = threadIdx.x;
  const int rowg = tid >> 4, colg = tid & 15;
  const int r8 = rowg * 8, c4 = colg * 4;
  __shared__ float At[64][68];
  __shared__ float Bs[64][132];
  __shared__ float lgam[64];
  if (tid < 64) lgam[tid] = gam[(size_t)task * 64 + tid];
  __syncthreads();
  const int t2 = tid >> 1, dh = (tid & 1) * 32;
  {
    const float* src = q + (((size_t)b * T_ + t0 + t2) * H_ + h) * DK_ + dh;
    const float sc = lgam[t2];
#pragma unroll
    for (int i = 0; i < 8; ++i) {
      const float4 v = ((const float4*)src)[i];
      At[dh + 4 * i + 0][t2] = v.x * sc; At[dh + 4 * i + 1][t2] = v.y * sc;
      At[dh + 4 * i + 2][t2] = v.z * sc; At[dh + 4 * i + 3][t2] = v.w * sc;
    }
  }
  {
    const float* src = Sst + (size_t)task * 8192 + t2 * 128 + (tid & 1) * 64;
    float* dst = &Bs[t2][(tid & 1) * 64];
#pragma unroll
    for (int i = 0; i < 16; ++i) ((float4*)dst)[i] = ((const float4*)src)[i];
  }
  __syncthreads();
  float acc[8][8];
#pragma unroll
  for (int i = 0; i < 8; ++i)
#pragma unroll
    for (int c = 0; c < 8; ++c) acc[i][c] = 0.f;
#pragma unroll 1
  for (int ph = 0; ph < 2; ++ph) {
    for (int kb = 0; kb < 64; kb += 4) {
#pragma unroll
      for (int j = 0; j < 4; ++j) {
        const float4 alo = *(const float4*)&At[kb + j][r8];
        const float4 ahi = *(const float4*)&At[kb + j][r8 + 4];
        const float4 blo = *(const float4*)&Bs[kb + j][c4];
        const float4 bhi = *(const float4*)&Bs[kb + j][c4 + 64];
        const float av[8] = {alo.x, alo.y, alo.z, alo.w, ahi.x, ahi.y, ahi.z, ahi.w};
        const float bv[8] = {blo.x, blo.y, blo.z, blo.w, bhi.x, bhi.y, bhi.z, bhi.w};
#pragma unroll
        for (int i = 0; i < 8; ++i)
#pragma unroll
          for (int c = 0; c < 8; ++c) acc[i][c] += av[i] * bv[c];
      }
    }
    if (ph == 0) {
      __syncthreads();
      {
        const float* src = qkd + (size_t)task * 4096 + t2 * 64 + dh;
#pragma unroll
        for (int i = 0; i < 8; ++i) {
          const float4 v = ((const float4*)src)[i];
          At[dh + 4 * i + 0][t2] = v.x; At[dh + 4 * i + 1][t2] = v.y;
          At[dh + 4 * i + 2][t2] = v.z; At[dh + 4 * i + 3][t2] = v.w;
        }
      }
      {
        const float* src = ub + (((size_t)b * T_ + t0 + t2) * H_ + h) * DV_ + (tid & 1) * 64;
        float* dst = &Bs[t2][(tid & 1) * 64];
#pragma unroll
        for (int i = 0; i < 16; ++i) ((float4*)dst)[i] = ((const float4*)src)[i];
      }
      __syncthreads();
    }
  }
#pragma unroll
  for (int i = 0; i < 8; ++i) {
    float pr = 0.f;
#pragma unroll
    for (int c = 0; c < 8; ++c) pr += acc[i][c] * acc[i][c];
    pr += __shfl_xor(pr, 1, 64);
    pr += __shfl_xor(pr, 2, 64);
    pr += __shfl_xor(pr, 4, 64);
    pr += __shfl_xor(pr, 8, 64);
    const float rms = rsqrtf(pr / (float)DV_ + 1e-5f);
    const size_t rb = (((size_t)b * T_ + t0 + r8 + i) * H_ + h) * DV_;
    const float4 glo = *(const float4*)(gate + rb + c4);
    const float4 ghi = *(const float4*)(gate + rb + c4 + 64);
    const float gv[8] = {glo.x, glo.y, glo.z, glo.w, ghi.x, ghi.y, ghi.z, ghi.w};
    unsigned short outv[8];
#pragma unroll
    for (int c = 0; c < 8; ++c) {
      const int col = (c < 4) ? c4 + c : c4 + 60 + c;
      const float gg = gv[c];
      const float val = acc[i][c] * rms * onw[col] * gg * (1.f / (1.f + __expf(-gg)));
      const __hip_bfloat16 bfv = __float2bfloat16(val);
      outv[c] = *(const unsigned short*)&bfv;
    }
    *(ushort4*)((unsigned short*)go + rb + c4) =
        make_ushort4(outv[0], outv[1], outv[2], outv[3]);
    *(ushort4*)((unsigned short*)go + rb + c4 + 64) =
        make_ushort4(outv[4], outv[5], outv[6], outv[7]);
  }
}

// ---------------------------------------------------------------------------
extern "C" void kernel_launch(void* const* d_in, const int* in_sizes, int n_in,
                              void* d_out, int out_size, void* d_ws, size_t ws_size,
                              hipStream_t stream) {
  const float* x    = (const float*)d_in[0];
  const float* n1w  = (const float*)d_in[1];
  const float* n2w  = (const float*)d_in[2];
  const float* Wq   = (const float*)d_in[3];
  const float* Wk   = (const float*)d_in[4];
  const float* Wv   = (const float*)d_in[5];
  const float* cq   = (const float*)d_in[6];
  const float* ck   = (const float*)d_in[7];
  const float* cv   = (const float*)d_in[8];
  const float* Wa   = (const float*)d_in[9];
  const float* Wb   = (const float*)d_in[10];
  const float* dtb  = (const float*)d_in[11];
  const float* Alog = (const float*)d_in[12];
  const float* Wg   = (const float*)d_in[13];
  const float* onw  = (const float*)d_in[14];
  const float* Wo   = (const float*)d_in[15];
  const float* W1   = (const float*)d_in[16];
  const float* W3   = (const float*)d_in[17];
  const float* W2   = (const float*)d_in[18];
  float* out = (float*)d_out;
  float* ws  = (float*)d_ws;

  const size_t SZ_MD = (size_t)M_ * D_;          // 2M floats
  const size_t SZ_MV = (size_t)M_ * H_ * DV_;    // 4M floats
  float* h    = ws;                               // [0,2M)
  float* pq   = ws + SZ_MD;                       // [2M,4M)  -> QKd -> y1
  float* pk   = ws + 2 * SZ_MD;                   // [4M,6M)  -> KdT
  float* pv   = ws + 3 * SZ_MD;                   // [6M,10M) -> S_store -> a1
  float* gate = ws + 3 * SZ_MD + SZ_MV;           // [10M,14M)
  float* qb   = ws + 3 * SZ_MD + 2 * SZ_MV;       // [14M,16M)
  float* kb   = ws + 4 * SZ_MD + 2 * SZ_MV;       // [16M,18M) in-place W
  float* vb   = ws + 5 * SZ_MD + 2 * SZ_MV;       // [18M,22M) in-place u -> Û
  float* Sst  = pv;
  float* y1   = pq;
  float* a1   = pv;
  float* smalls = ws + 5 * SZ_MD + 3 * SZ_MV;     // 22M
  float* pa  = smalls;
  float* pb  = pa + (size_t)M_ * H_;
  float* gv  = pb + (size_t)M_ * H_;
  float* bv  = gv + (size_t)M_ * H_;
  float* gam = bv + (size_t)M_ * H_;
  __hip_bfloat16* h_bf  = (__hip_bfloat16*)vb;
  __hip_bfloat16* wb1   = (__hip_bfloat16*)kb;
  __hip_bfloat16* wb2   = (__hip_bfloat16*)vb;
  __hip_bfloat16* go_bf = (__hip_bfloat16*)h;
  __hip_bfloat16* h2_bf = (__hip_bfloat16*)h;
  __hip_bfloat16* a1b   = (__hip_bfloat16*)qb;

  const dim3 blk256(256);
  const dim3 g_tr1024_1024(1024 / 32, 1024 / 32);
  const dim3 g_tr1024_2048(2048 / 32, 1024 / 32);
  const dim3 g_tr2048_1024(1024 / 32, 2048 / 32);
  const dim3 g_tr1024_2816(2816 / 32, 1024 / 32);
  const dim3 g_tr2816_1024(1024 / 32, 2816 / 32);

  rmsnorm_k<<<dim3(M_), blk256, 0, stream>>>(x, n1w, h, h_bf, D_, 1e-6f);
  transpose_bf16_k<<<g_tr1024_1024, blk256, 0, stream>>>(Wq, wb1, D_, 1024);
  mfma_gemm_k<64><<<dim3(1024 / 64, M_ / 128), blk256, 0, stream>>>(h_bf, wb1, nullptr, pq, M_, 1024, D_, 0);
  transpose_bf16_k<<<g_tr1024_1024, blk256, 0, stream>>>(Wk, wb1, D_, 1024);
  mfma_gemm_k<64><<<dim3(1024 / 64, M_ / 128), blk256, 0, stream>>>(h_bf, wb1, nullptr, pk, M_, 1024, D_, 0);
  transpose_bf16_k<<<g_tr1024_2048, blk256, 0, stream>>>(Wv, wb1, D_, 2048);
  mfma_gemm_k<128><<<dim3(2048 / 128, M_ / 128), blk256, 0, stream>>>(h_bf, wb1, nullptr, pv, M_, 2048, D_, 0);
  transpose_bf16_k<<<g_tr1024_2048, blk256, 0, stream>>>(Wg, wb1, D_, 2048);
  mfma_gemm_k<128><<<dim3(2048 / 128, M_ / 128), blk256, 0, stream>>>(h_bf, wb1, nullptr, gate, M_, 2048, D_, 0);
  skinny_k<<<dim3(M_), blk256, 0, stream>>>(h, Wa, Wb, pa, pb, D_);
  conv_silu_l2_k<<<dim3(M_), blk256, 0, stream>>>(pq, cq, qb, 0.125f);
  conv_silu_l2_k<<<dim3(M_), blk256, 0, stream>>>(pk, ck, kb, 1.0f);
  conv_silu_k<<<dim3(M_), blk256, 0, stream>>>(pv, cv, vb, H_ * DV_);
  beta_g_k<<<dim3((M_ * H_ + 255) / 256), blk256, 0, stream>>>(pa, pb, dtb, Alog, gv, bv, M_ * H_);
  chunk_prep_k<<<dim3(32 * NCH), blk256, 0, stream>>>(qb, kb, vb, gv, bv, pq, pk, gam);
  chunk_rec_k<<<dim3(32 * 8), dim3(64), 0, stream>>>(kb, vb, pk, gam, Sst);
  chunk_o_k<<<dim3(32 * NCH), dim3(128), 0, stream>>>(qb, pq, vb, Sst, gam, gate, onw, go_bf);
  transpose_bf16_k<<<g_tr2048_1024, blk256, 0, stream>>>(Wo, wb2, H_ * DV_, 1024);
  mfma_gemm_k<64><<<dim3(1024 / 64, M_ / 128), blk256, 0, stream>>>(go_bf, wb2, x, y1, M_, 1024, H_ * DV_, 1);
  rmsnorm_k<<<dim3(M_), blk256, 0, stream>>>(y1, n2w, nullptr, h2_bf, D_, 1e-6f);
  transpose_bf16_k<<<g_tr1024_2816, blk256, 0, stream>>>(W1, wb2, D_, FH_);
  mfma_gemm_k<128><<<dim3(FH_ / 128, M_ / 128), blk256, 0, stream>>>(h2_bf, wb2, nullptr, a1, M_, FH_, D_, 0);
  transpose_bf16_k<<<g_tr1024_2816, blk256, 0, stream>>>(W3, wb2, D_, FH_);
  mfma_gemm_k<128><<<dim3(FH_ / 128, M_ / 128), blk256, 0, stream>>>(h2_bf, wb2, a1, a1b, M_, FH_, D_, 2);
  transpose_bf16_k<<<g_tr2816_1024, blk256, 0, stream>>>(W2, wb2, FH_, 1024);
  mfma_gemm_k<64><<<dim3(1024 / 64, M_ / 128), blk256, 0, stream>>>(a1b, wb2, y1, out, M_, 1024, FH_, 1);
}